// Round 11
// baseline (308.796 us; speedup 1.0000x reference)
//
#include <hip/hip_runtime.h>

// bf16 handled as raw ushort (bf16 = top 16 bits of fp32).
typedef unsigned short bfu;
typedef unsigned int u32;
typedef __attribute__((ext_vector_type(8))) short bf16x8;   // 8 bf16 = 4 VGPRs
typedef __attribute__((ext_vector_type(4))) float f32x4;

#define SCALE_F 0.17677669529663687f

__device__ __forceinline__ bfu f2b(float f) {
  unsigned int u = __float_as_uint(f);
  u += 0x7fffu + ((u >> 16) & 1u);   // round-to-nearest-even
  return (bfu)(u >> 16);
}
__device__ __forceinline__ unsigned pk2(float a, float b) {
  return ((unsigned)f2b(b) << 16) | (unsigned)f2b(a);
}
__device__ __forceinline__ void gload_lds16(const void* g, void* l) {
  __builtin_amdgcn_global_load_lds(
      (const __attribute__((address_space(1))) u32*)g,
      (__attribute__((address_space(3))) u32*)l, 16, 0, 0);
}

// Prep: cvt w_qkv [768][256] f32 -> bf16 (N x K), w_out [256][256] likewise,
// and gather the 64x64 relative-position bias table (f32).
__global__ void prep_kernel(const float* __restrict__ wq, const float* __restrict__ wo,
                            const float* __restrict__ pe, const int* __restrict__ rel,
                            bfu* __restrict__ wqB, bfu* __restrict__ woB,
                            float* __restrict__ bias)
{
  int t = blockIdx.x * 256 + threadIdx.x;
  if (t < 196608) wqB[t] = f2b(wq[t]);
  if (t < 65536)  woB[t] = f2b(wo[t]);
  if (t < 4096)   { int r0 = rel[2 * t], r1 = rel[2 * t + 1]; bias[t] = pe[r0 * 15 + r1]; }
}

// Fused qkv-projection + window attention. One block per (bl, win), 1024 thr =
// 16 waves; 2 waves per head (token halves s=0/1). Phases separated by
// block-wide __syncthreads (no double-buffer race surface).
// LDS: xwin [64 tok][256 c] bf16 unit-swizzled (32 KB) + per-head
// {qs[64][40], ks[64][40] (80 B stride), vs[32][72] (144 B), inv[64] f32,
//  ps 8 KB aliasing qs+ks} = 15104 B. Total 153600 B (1 block/CU, 16 waves).
__global__ __launch_bounds__(1024, 4)
void qkv_attn(const float* __restrict__ x, const bfu* __restrict__ wqB,
              const float* __restrict__ b_qkv, const float* __restrict__ bias,
              bfu* __restrict__ aout)
{
  __shared__ __align__(16) char slds[153600];
  const int t = threadIdx.x;
  const int lane = t & 63, wid = t >> 6;       // 16 waves
  const int l15 = lane & 15, l4 = lane >> 4;
  const int h = wid >> 1, s = wid & 1;         // head, token-half
  const int blwin = blockIdx.x;
  const int bl = blwin >> 8, win = blwin & 255;

  // ---- stage x window: wave stages 4 tokens (y-row h, quarter s) ----
  {
    int y = ((win >> 4) << 3) | h;
    size_t rowbase = (((size_t)bl * 16384) + (size_t)y * 128 + ((win & 15) << 3)) * 256;
    const float* px = x + rowbase + (size_t)(s << 2) * 256 + (lane << 2);
    #pragma unroll
    for (int i = 0; i < 4; ++i) {
      float4 v = *(const float4*)(px + i * 256);
      uint2 d; d.x = pk2(v.x, v.y); d.y = pk2(v.z, v.w);
      int tok = (h << 3) | (s << 2) | i;
      *(uint2*)(slds + tok * 512 + (((lane >> 1) ^ (tok & 15)) << 4) + ((lane & 1) << 3)) = d;
    }
  }
  __syncthreads();

  char* wbl = slds + 32768 + h * 15104;
  char* qsB = wbl;
  char* ksB = wbl + 5120;
  char* vsB = wbl + 10240;
  float* invB = (float*)(wbl + 14848);
  char* psB = wbl;   // aliases qs+ks after they are consumed (post-barrier)

  // ---- fused Q/K/V mini-GEMMs over token half s ----
  const bfu* wQ = wqB + (size_t)(h * 32) * 256;
  const bfu* wK = wqB + (size_t)(256 + h * 32) * 256;
  const bfu* wV = wqB + (size_t)(512 + h * 32) * 256;
  const int woff = l15 * 256 + (l4 << 3);
  f32x4 aQ[2][2] = {}, aK[2][2] = {}, aV[2][2] = {};
  #pragma unroll
  for (int kt = 0; kt < 8; ++kt) {
    bf16x8 xf[2];
    #pragma unroll
    for (int m = 0; m < 2; ++m) {
      int tok = (s << 5) + (m << 4) + l15;
      int u = ((kt << 2) + l4) ^ (tok & 15);
      xf[m] = *(const bf16x8*)(slds + tok * 512 + (u << 4));
    }
    bf16x8 q0 = *(const bf16x8*)(wQ + woff + (kt << 5));
    bf16x8 q1 = *(const bf16x8*)(wQ + woff + (kt << 5) + 4096);
    bf16x8 k0 = *(const bf16x8*)(wK + woff + (kt << 5));
    bf16x8 k1 = *(const bf16x8*)(wK + woff + (kt << 5) + 4096);
    bf16x8 v0 = *(const bf16x8*)(wV + woff + (kt << 5));
    bf16x8 v1 = *(const bf16x8*)(wV + woff + (kt << 5) + 4096);
    #pragma unroll
    for (int m = 0; m < 2; ++m) {
      aQ[0][m] = __builtin_amdgcn_mfma_f32_16x16x32_bf16(q0, xf[m], aQ[0][m], 0, 0, 0);
      aQ[1][m] = __builtin_amdgcn_mfma_f32_16x16x32_bf16(q1, xf[m], aQ[1][m], 0, 0, 0);
      aK[0][m] = __builtin_amdgcn_mfma_f32_16x16x32_bf16(k0, xf[m], aK[0][m], 0, 0, 0);
      aK[1][m] = __builtin_amdgcn_mfma_f32_16x16x32_bf16(k1, xf[m], aK[1][m], 0, 0, 0);
      aV[m][0] = __builtin_amdgcn_mfma_f32_16x16x32_bf16(xf[m], v0, aV[m][0], 0, 0, 0);
      aV[m][1] = __builtin_amdgcn_mfma_f32_16x16x32_bf16(xf[m], v1, aV[m][1], 0, 0, 0);
    }
  }

  // Q/K epilogue (swapped: D[c][tok], r spans c): qs/ks [tok][32c] stride 80 B.
  {
    const float* bQ = b_qkv + h * 32;
    const float* bK = b_qkv + 256 + h * 32;
    #pragma unroll
    for (int n = 0; n < 2; ++n) {
      int c0 = (n << 4) + (l4 << 2);
      float4 bbq = *(const float4*)(bQ + c0);
      float4 bbk = *(const float4*)(bK + c0);
      #pragma unroll
      for (int m = 0; m < 2; ++m) {
        int tok = (s << 5) + (m << 4) + l15;
        f32x4 a = aQ[n][m];
        ushort4 u4;
        u4.x = f2b(a[0] + bbq.x); u4.y = f2b(a[1] + bbq.y);
        u4.z = f2b(a[2] + bbq.z); u4.w = f2b(a[3] + bbq.w);
        *(ushort4*)(qsB + tok * 80 + (c0 << 1)) = u4;
        a = aK[n][m];
        u4.x = f2b(a[0] + bbk.x); u4.y = f2b(a[1] + bbk.y);
        u4.z = f2b(a[2] + bbk.z); u4.w = f2b(a[3] + bbk.w);
        *(ushort4*)(ksB + tok * 80 + (c0 << 1)) = u4;
      }
    }
  }
  // V epilogue (normal: D[tok][c], r spans tok) -> vs [c][tok] stride 144 B.
  {
    const float* bV = b_qkv + 512 + h * 32;
    #pragma unroll
    for (int m = 0; m < 2; ++m) {
      int tok0 = (s << 5) + (m << 4) + (l4 << 2);
      #pragma unroll
      for (int n = 0; n < 2; ++n) {
        int c = (n << 4) + l15;
        float bbv = bV[c];
        f32x4 a = aV[m][n];
        ushort4 u4;
        u4.x = f2b(a[0] + bbv); u4.y = f2b(a[1] + bbv);
        u4.z = f2b(a[2] + bbv); u4.w = f2b(a[3] + bbv);
        *(ushort4*)(vsB + c * 144 + (tok0 << 1)) = u4;
      }
    }
  }
  __syncthreads();   // all q/k/v published

  // ---- attention: wave owns q-rows s*32..s*32+31 ----
  bf16x8 qf[2], kf[4];
  #pragma unroll
  for (int i = 0; i < 2; ++i)
    qf[i] = *(const bf16x8*)(qsB + ((s << 5) + (i << 4) + l15) * 80 + (l4 << 4));
  #pragma unroll
  for (int j = 0; j < 4; ++j)
    kf[j] = *(const bf16x8*)(ksB + ((j << 4) + l15) * 80 + (l4 << 4));

  // S^T[j][i] = mfma(K, Q): reg r -> j = mj*16+l4*4+r; col i local ni.
  f32x4 st[4][2] = {};
  #pragma unroll
  for (int mj = 0; mj < 4; ++mj)
    #pragma unroll
    for (int ni = 0; ni < 2; ++ni)
      st[mj][ni] = __builtin_amdgcn_mfma_f32_16x16x32_bf16(kf[mj], qf[ni], st[mj][ni], 0, 0, 0);

  // scale + bias
  #pragma unroll
  for (int ni = 0; ni < 2; ++ni) {
    int i = (s << 5) + (ni << 4) + l15;
    #pragma unroll
    for (int mj = 0; mj < 4; ++mj) {
      float4 bb = *(const float4*)(bias + i * 64 + (mj << 4) + (l4 << 2));
      st[mj][ni][0] = fmaf(st[mj][ni][0], SCALE_F, bb.x);
      st[mj][ni][1] = fmaf(st[mj][ni][1], SCALE_F, bb.y);
      st[mj][ni][2] = fmaf(st[mj][ni][2], SCALE_F, bb.z);
      st[mj][ni][3] = fmaf(st[mj][ni][3], SCALE_F, bb.w);
    }
  }
  __syncthreads();   // qf/kf consumed block-wide; safe to overwrite qs/ks with P

  // softmax per owned q-row; unnormalized P -> swizzled psB (own rows only).
  #pragma unroll
  for (int ni = 0; ni < 2; ++ni) {
    float mx = st[0][ni][0];
    #pragma unroll
    for (int mj = 0; mj < 4; ++mj)
      #pragma unroll
      for (int r = 0; r < 4; ++r)
        mx = fmaxf(mx, st[mj][ni][r]);
    mx = fmaxf(mx, __shfl_xor(mx, 16));
    mx = fmaxf(mx, __shfl_xor(mx, 32));
    float sum = 0.f;
    #pragma unroll
    for (int mj = 0; mj < 4; ++mj)
      #pragma unroll
      for (int r = 0; r < 4; ++r) {
        float p = __expf(st[mj][ni][r] - mx);
        st[mj][ni][r] = p;
        sum += p;
      }
    sum += __shfl_xor(sum, 16);
    sum += __shfl_xor(sum, 32);
    int i2 = (s << 5) + (ni << 4) + l15;
    if (l4 == 0) invB[i2] = 1.0f / sum;
    const int swz = (i2 & 7) << 4;
    #pragma unroll
    for (int mj = 0; mj < 4; ++mj) {
      uint2 val;
      val.x = pk2(st[mj][ni][0], st[mj][ni][1]);
      val.y = pk2(st[mj][ni][2], st[mj][ni][3]);
      *(uint2*)(psB + i2 * 128 + (((mj << 5) + (l4 << 3)) ^ swz)) = val;
    }
  }

  // PV: O[i][c] = sum_j P[i][j] * Vt[c][j]; own rows, full V.
  bf16x8 vf[2][2];
  #pragma unroll
  for (int nj = 0; nj < 2; ++nj)
    #pragma unroll
    for (int ks = 0; ks < 2; ++ks)
      vf[nj][ks] = *(const bf16x8*)(vsB + ((nj << 4) + l15) * 144 + (ks << 6) + (l4 << 4));

  f32x4 oacc[2][2] = {};
  #pragma unroll
  for (int mi = 0; mi < 2; ++mi) {
    int i = (s << 5) + (mi << 4) + l15;
    int swz = (i & 7) << 4;
    bf16x8 pf0 = *(const bf16x8*)(psB + i * 128 + ((l4 << 4) ^ swz));
    bf16x8 pf1 = *(const bf16x8*)(psB + i * 128 + ((64 + (l4 << 4)) ^ swz));
    #pragma unroll
    for (int nj = 0; nj < 2; ++nj) {
      oacc[mi][nj] = __builtin_amdgcn_mfma_f32_16x16x32_bf16(pf0, vf[nj][0], oacc[mi][nj], 0, 0, 0);
      oacc[mi][nj] = __builtin_amdgcn_mfma_f32_16x16x32_bf16(pf1, vf[nj][1], oacc[mi][nj], 0, 0, 0);
    }
  }

  // epilogue: row i = s*32 + mi*16 + l4*4 + r, col c = nj*16 + l15
  #pragma unroll
  for (int mi = 0; mi < 2; ++mi) {
    #pragma unroll
    for (int r = 0; r < 4; ++r) {
      int tok = (s << 5) + (mi << 4) + (l4 << 2) + r;
      float inv = invB[tok];
      int y = ((win >> 4) << 3) | (tok >> 3);
      int xp = ((win & 15) << 3) | (tok & 7);
      size_t p = ((size_t)bl * 128 + y) * 128 + xp;
      bfu* dst = aout + p * 256 + h * 32;
      #pragma unroll
      for (int nj = 0; nj < 2; ++nj)
        dst[(nj << 4) + l15] = f2b(oacc[mi][nj][r] * inv);
    }
  }
}

// Out-projection GEMM (round-8-verified): C[m][n] = sum_k A[m][k]*B[n][k] + bias[n].
// BK=32, double-buffered, STAGE(next) -> compute -> full barrier. f32 out.
template<int NBN>
__global__ __launch_bounds__(256)
void mfma_gemm(const bfu* __restrict__ A, const bfu* __restrict__ B,
               const float* __restrict__ bias, float* __restrict__ out)
{
  __shared__ __align__(16) char lds[32768];
  const int t = threadIdx.x;
  const int lane = t & 63;
  const int l15 = lane & 15, l4 = lane >> 4;
  const int wid = t >> 6;
  const int wr = wid >> 1, wc = wid & 1;

  const int L = blockIdx.x;
  const int chunk = (NBN * 1024) >> 3;
  const int w = (L & 7) * chunk + (L >> 3);
  const int bm = w / NBN, bn = w % NBN;

  const int goff = (lane >> 2) * 256 + (((lane & 3) ^ ((lane >> 3) & 3)) << 3);
  const bfu* Ab = A + (((size_t)(bm * 128)) << 8) + goff;
  const bfu* Bb = B + (((size_t)(bn * 128)) << 8) + goff;

  f32x4 acc[4][4] = {};

  auto STAGE = [&](int buf, int kt) {
    char* dst = lds + (buf << 14);
    const bfu* ga = Ab + (kt << 5);
    const bfu* gb = Bb + (kt << 5);
    #pragma unroll
    for (int r = 0; r < 2; ++r) {
      int rowg = (wid << 5) + (r << 4);
      gload_lds16(ga + (size_t)rowg * 256, dst + (rowg << 6));
      gload_lds16(gb + (size_t)rowg * 256, dst + 8192 + (rowg << 6));
    }
  };

  STAGE(0, 0);
  __syncthreads();

  for (int kt = 0; kt < 8; ++kt) {
    if (kt < 7) STAGE((kt + 1) & 1, kt + 1);
    const char* bufp = lds + ((kt & 1) << 14);

    bf16x8 af[4], bfr[4];
    #pragma unroll
    for (int ms = 0; ms < 4; ++ms) {
      int row = (wr << 6) + (ms << 4) + l15;
      int u = (l4 ^ ((row >> 1) & 3)) << 4;
      af[ms] = *(const bf16x8*)(bufp + (row << 6) + u);
    }
    #pragma unroll
    for (int ns = 0; ns < 4; ++ns) {
      int row = (wc << 6) + (ns << 4) + l15;
      int u = (l4 ^ ((row >> 1) & 3)) << 4;
      bfr[ns] = *(const bf16x8*)(bufp + 8192 + (row << 6) + u);
    }
    #pragma unroll
    for (int ms = 0; ms < 4; ++ms)
      #pragma unroll
      for (int ns = 0; ns < 4; ++ns)
        acc[ms][ns] = __builtin_amdgcn_mfma_f32_16x16x32_bf16(af[ms], bfr[ns], acc[ms][ns], 0, 0, 0);
    if (kt < 7) __syncthreads();
  }

  #pragma unroll
  for (int ns = 0; ns < 4; ++ns) {
    int n = bn * 128 + (wc << 6) + (ns << 4) + l15;
    float bb = bias[n];
    #pragma unroll
    for (int ms = 0; ms < 4; ++ms) {
      int m = bm * 128 + (wr << 6) + (ms << 4) + (l4 << 2);
      #pragma unroll
      for (int r = 0; r < 4; ++r)
        out[((size_t)(m + r) << 8) + n] = acc[ms][ns][r] + bb;
    }
  }
}

extern "C" void kernel_launch(void* const* d_in, const int* in_sizes, int n_in,
                              void* d_out, int out_size, void* d_ws, size_t ws_size,
                              hipStream_t stream)
{
  const float* x     = (const float*)d_in[0];
  const float* w_qkv = (const float*)d_in[1];
  const float* b_qkv = (const float*)d_in[2];
  const float* w_out = (const float*)d_in[3];
  const float* b_out = (const float*)d_in[4];
  const float* pe    = (const float*)d_in[5];
  const int*   rel   = (const int*)d_in[6];
  float* out = (float*)d_out;

  char* ws = (char*)d_ws;
  bfu*   attn_ws = (bfu*)(ws);                 // [131072][256] bf16 = 64 MiB
  float* bias_ws = (float*)(ws + 67108864);    // 4096 f32
  bfu*   wqB     = (bfu*)(ws + 67125248);      // 196608 bf16 [768][256]
  bfu*   woB     = (bfu*)(ws + 67518464);      // 65536 bf16 [256][256]

  prep_kernel<<<768, 256, 0, stream>>>(w_qkv, w_out, pe, rel, wqB, woB, bias_ws);
  qkv_attn<<<2048, 1024, 0, stream>>>(x, wqB, b_qkv, bias_ws, attn_ws);
  mfma_gemm<2><<<2048, 256, 0, stream>>>(attn_ws, woB, b_out, out);
}

// Round 12
// 212.546 us; speedup vs baseline: 1.4528x; 1.4528x over previous
//
#include <hip/hip_runtime.h>

// bf16 handled as raw ushort (bf16 = top 16 bits of fp32).
typedef unsigned short bfu;
typedef unsigned int u32;
typedef __attribute__((ext_vector_type(8))) short bf16x8;   // 8 bf16 = 4 VGPRs
typedef __attribute__((ext_vector_type(4))) float f32x4;

#define SCALE_F 0.17677669529663687f

__device__ __forceinline__ bfu f2b(float f) {
  unsigned int u = __float_as_uint(f);
  u += 0x7fffu + ((u >> 16) & 1u);   // round-to-nearest-even
  return (bfu)(u >> 16);
}
__device__ __forceinline__ unsigned pk2(float a, float b) {
  return ((unsigned)f2b(b) << 16) | (unsigned)f2b(a);
}
__device__ __forceinline__ void gload_lds16(const void* g, void* l) {
  __builtin_amdgcn_global_load_lds(
      (const __attribute__((address_space(1))) u32*)g,
      (__attribute__((address_space(3))) u32*)l, 16, 0, 0);
}

// Prep: cvt w_qkv [768][256] f32 -> bf16 (N x K), w_out [256][256] likewise,
// and gather the 64x64 relative-position bias table (f32).
__global__ void prep_kernel(const float* __restrict__ wq, const float* __restrict__ wo,
                            const float* __restrict__ pe, const int* __restrict__ rel,
                            bfu* __restrict__ wqB, bfu* __restrict__ woB,
                            float* __restrict__ bias)
{
  int t = blockIdx.x * 256 + threadIdx.x;
  if (t < 196608) wqB[t] = f2b(wq[t]);
  if (t < 65536)  woB[t] = f2b(wo[t]);
  if (t < 4096)   { int r0 = rel[2 * t], r1 = rel[2 * t + 1]; bias[t] = pe[r0 * 15 + r1]; }
}

// Fused qkv-projection + window attention. One block per (bl, win), 512 thr,
// 8 waves; wave = head (round-10-verified structure). Single change vs round 10:
// the three mini-GEMMs are FUSED into one kt loop (24 accumulators, 24
// independent MFMA chains per kt) so weight/x loads pipeline across kt.
// LDS: xwin [64 tok][256 c] bf16 unit-swizzled (32 KB) + per-wave
// {qs[64][40], ks[64][40] (80 B stride), vs[32][72] (144 B), inv[64] f32,
//  ps 8 KB aliasing qs+ks} = 15104 B. Total 153600 B.
__global__ __launch_bounds__(512, 2)
void qkv_attn(const float* __restrict__ x, const bfu* __restrict__ wqB,
              const float* __restrict__ b_qkv, const float* __restrict__ bias,
              bfu* __restrict__ aout)
{
  __shared__ __align__(16) char slds[153600];
  const int t = threadIdx.x;
  const int lane = t & 63, wid = t >> 6;       // wid = head = staging y-row
  const int l15 = lane & 15, l4 = lane >> 4;
  const int blwin = blockIdx.x;
  const int bl = blwin >> 8, win = blwin & 255;

  // Stage x window: wave w stages y-row w (8 tokens x 256 ch) as bf16.
  // phys: slds[tok*512 + (u ^ (tok&15))*16 + sub], u = channel-unit (8 ch).
  {
    int y = ((win >> 4) << 3) | wid;
    size_t rowbase = (((size_t)bl * 16384) + (size_t)y * 128 + ((win & 15) << 3)) * 256;
    const float* px = x + rowbase + (lane << 2);
    #pragma unroll
    for (int i = 0; i < 8; ++i) {
      float4 v = *(const float4*)(px + i * 256);
      uint2 d; d.x = pk2(v.x, v.y); d.y = pk2(v.z, v.w);
      int tok = (wid << 3) | i;
      *(uint2*)(slds + tok * 512 + (((lane >> 1) ^ (tok & 15)) << 4) + ((lane & 1) << 3)) = d;
    }
  }
  __syncthreads();

  char* wbl = slds + 32768 + wid * 15104;
  char* qsB = wbl;
  char* ksB = wbl + 5120;
  char* vsB = wbl + 10240;
  float* invB = (float*)(wbl + 14848);
  char* psB = wbl;   // aliases qs/ks AFTER qf/kf frags are in registers
  const int h = wid;

  // ---- fused Q/K/V mini-GEMMs (one kt loop, 24 acc chains) ----
  {
    const bfu* wQ = wqB + (size_t)(h * 32) * 256;
    const bfu* wK = wqB + (size_t)(256 + h * 32) * 256;
    const bfu* wV = wqB + (size_t)(512 + h * 32) * 256;
    const int woff = l15 * 256 + (l4 << 3);
    f32x4 aQ[2][4] = {}, aK[2][4] = {}, aV[4][2] = {};
    #pragma unroll
    for (int kt = 0; kt < 8; ++kt) {
      bf16x8 xf[4];
      #pragma unroll
      for (int m = 0; m < 4; ++m) {
        int tok = (m << 4) + l15;
        int u = ((kt << 2) + l4) ^ (tok & 15);
        xf[m] = *(const bf16x8*)(slds + tok * 512 + (u << 4));
      }
      bf16x8 q0 = *(const bf16x8*)(wQ + woff + (kt << 5));
      bf16x8 q1 = *(const bf16x8*)(wQ + woff + (kt << 5) + 4096);
      bf16x8 k0 = *(const bf16x8*)(wK + woff + (kt << 5));
      bf16x8 k1 = *(const bf16x8*)(wK + woff + (kt << 5) + 4096);
      bf16x8 v0 = *(const bf16x8*)(wV + woff + (kt << 5));
      bf16x8 v1 = *(const bf16x8*)(wV + woff + (kt << 5) + 4096);
      #pragma unroll
      for (int m = 0; m < 4; ++m) {
        aQ[0][m] = __builtin_amdgcn_mfma_f32_16x16x32_bf16(q0, xf[m], aQ[0][m], 0, 0, 0);
        aQ[1][m] = __builtin_amdgcn_mfma_f32_16x16x32_bf16(q1, xf[m], aQ[1][m], 0, 0, 0);
        aK[0][m] = __builtin_amdgcn_mfma_f32_16x16x32_bf16(k0, xf[m], aK[0][m], 0, 0, 0);
        aK[1][m] = __builtin_amdgcn_mfma_f32_16x16x32_bf16(k1, xf[m], aK[1][m], 0, 0, 0);
        aV[m][0] = __builtin_amdgcn_mfma_f32_16x16x32_bf16(xf[m], v0, aV[m][0], 0, 0, 0);
        aV[m][1] = __builtin_amdgcn_mfma_f32_16x16x32_bf16(xf[m], v1, aV[m][1], 0, 0, 0);
      }
    }

    // Q/K epilogue (swapped: D[c][tok], r spans c): qs/ks [tok][32c] stride 80 B.
    const float* bQ = b_qkv + h * 32;
    const float* bK = b_qkv + 256 + h * 32;
    #pragma unroll
    for (int n = 0; n < 2; ++n) {
      int c0 = (n << 4) + (l4 << 2);
      float4 bbq = *(const float4*)(bQ + c0);
      float4 bbk = *(const float4*)(bK + c0);
      #pragma unroll
      for (int m = 0; m < 4; ++m) {
        int tok = (m << 4) + l15;
        f32x4 a = aQ[n][m];
        ushort4 u4;
        u4.x = f2b(a[0] + bbq.x); u4.y = f2b(a[1] + bbq.y);
        u4.z = f2b(a[2] + bbq.z); u4.w = f2b(a[3] + bbq.w);
        *(ushort4*)(qsB + tok * 80 + (c0 << 1)) = u4;
        a = aK[n][m];
        u4.x = f2b(a[0] + bbk.x); u4.y = f2b(a[1] + bbk.y);
        u4.z = f2b(a[2] + bbk.z); u4.w = f2b(a[3] + bbk.w);
        *(ushort4*)(ksB + tok * 80 + (c0 << 1)) = u4;
      }
    }
    // V epilogue (normal: D[tok][c], r spans tok) -> vs [c][tok] stride 144 B.
    const float* bV = b_qkv + 512 + h * 32;
    #pragma unroll
    for (int m = 0; m < 4; ++m) {
      int tok0 = (m << 4) + (l4 << 2);
      #pragma unroll
      for (int n = 0; n < 2; ++n) {
        int c = (n << 4) + l15;
        float bbv = bV[c];
        f32x4 a = aV[m][n];
        ushort4 u4;
        u4.x = f2b(a[0] + bbv); u4.y = f2b(a[1] + bbv);
        u4.z = f2b(a[2] + bbv); u4.w = f2b(a[3] + bbv);
        *(ushort4*)(vsB + c * 144 + (tok0 << 1)) = u4;
      }
    }
  }

  // ---- attention (round-10-verified per-wave structure) ----
  bf16x8 qf[4], kf[4];
  #pragma unroll
  for (int i = 0; i < 4; ++i) {
    qf[i] = *(const bf16x8*)(qsB + ((i << 4) + l15) * 80 + (l4 << 4));
    kf[i] = *(const bf16x8*)(ksB + ((i << 4) + l15) * 80 + (l4 << 4));
  }

  // S^T[j][i] = mfma(K, Q): reg r -> j = mj*16 + l4*4 + r; col i = ni*16 + l15.
  f32x4 st[4][4] = {};
  #pragma unroll
  for (int mj = 0; mj < 4; ++mj)
    #pragma unroll
    for (int ni = 0; ni < 4; ++ni)
      st[mj][ni] = __builtin_amdgcn_mfma_f32_16x16x32_bf16(kf[mj], qf[ni], st[mj][ni], 0, 0, 0);

  // scale + bias (bias table from global, L2-hot)
  #pragma unroll
  for (int ni = 0; ni < 4; ++ni) {
    int i = (ni << 4) + l15;
    #pragma unroll
    for (int mj = 0; mj < 4; ++mj) {
      float4 bb = *(const float4*)(bias + i * 64 + (mj << 4) + (l4 << 2));
      st[mj][ni][0] = fmaf(st[mj][ni][0], SCALE_F, bb.x);
      st[mj][ni][1] = fmaf(st[mj][ni][1], SCALE_F, bb.y);
      st[mj][ni][2] = fmaf(st[mj][ni][2], SCALE_F, bb.z);
      st[mj][ni][3] = fmaf(st[mj][ni][3], SCALE_F, bb.w);
    }
  }

  // qf/kf are in registers; ensure outstanding LDS reads retired before
  // overwriting their space with P (psB aliases qsB/ksB).
  asm volatile("s_waitcnt lgkmcnt(0)" ::: "memory");
  __builtin_amdgcn_sched_barrier(0);

  // softmax over j per owned q-row; unnormalized P -> swizzled psB.
  #pragma unroll
  for (int ni = 0; ni < 4; ++ni) {
    float mx = st[0][ni][0];
    #pragma unroll
    for (int mj = 0; mj < 4; ++mj)
      #pragma unroll
      for (int r = 0; r < 4; ++r)
        mx = fmaxf(mx, st[mj][ni][r]);
    mx = fmaxf(mx, __shfl_xor(mx, 16));
    mx = fmaxf(mx, __shfl_xor(mx, 32));
    float sum = 0.f;
    #pragma unroll
    for (int mj = 0; mj < 4; ++mj)
      #pragma unroll
      for (int r = 0; r < 4; ++r) {
        float p = __expf(st[mj][ni][r] - mx);
        st[mj][ni][r] = p;
        sum += p;
      }
    sum += __shfl_xor(sum, 16);
    sum += __shfl_xor(sum, 32);
    int i2 = (ni << 4) + l15;
    if (l4 == 0) invB[i2] = 1.0f / sum;
    const int swz = (i2 & 7) << 4;
    #pragma unroll
    for (int mj = 0; mj < 4; ++mj) {
      uint2 val;
      val.x = pk2(st[mj][ni][0], st[mj][ni][1]);
      val.y = pk2(st[mj][ni][2], st[mj][ni][3]);
      *(uint2*)(psB + i2 * 128 + (((mj << 5) + (l4 << 3)) ^ swz)) = val;
    }
  }

  // PV: O[i][c] = sum_j P[i][j] * Vt[c][j]
  bf16x8 vf[2][2];
  #pragma unroll
  for (int nj = 0; nj < 2; ++nj)
    #pragma unroll
    for (int ks = 0; ks < 2; ++ks)
      vf[nj][ks] = *(const bf16x8*)(vsB + ((nj << 4) + l15) * 144 + (ks << 6) + (l4 << 4));

  f32x4 oacc[4][2] = {};
  #pragma unroll
  for (int mi = 0; mi < 4; ++mi) {
    int i = (mi << 4) + l15;
    int swz = (i & 7) << 4;
    bf16x8 pf0 = *(const bf16x8*)(psB + i * 128 + ((l4 << 4) ^ swz));
    bf16x8 pf1 = *(const bf16x8*)(psB + i * 128 + ((64 + (l4 << 4)) ^ swz));
    #pragma unroll
    for (int nj = 0; nj < 2; ++nj) {
      oacc[mi][nj] = __builtin_amdgcn_mfma_f32_16x16x32_bf16(pf0, vf[nj][0], oacc[mi][nj], 0, 0, 0);
      oacc[mi][nj] = __builtin_amdgcn_mfma_f32_16x16x32_bf16(pf1, vf[nj][1], oacc[mi][nj], 0, 0, 0);
    }
  }

  // epilogue: row i = mi*16 + l4*4 + r, col c = nj*16 + l15
  #pragma unroll
  for (int mi = 0; mi < 4; ++mi) {
    #pragma unroll
    for (int r = 0; r < 4; ++r) {
      int tok = (mi << 4) + (l4 << 2) + r;
      float inv = invB[tok];
      int y = ((win >> 4) << 3) | (tok >> 3);
      int xp = ((win & 15) << 3) | (tok & 7);
      size_t p = ((size_t)bl * 128 + y) * 128 + xp;
      bfu* dst = aout + p * 256 + h * 32;
      #pragma unroll
      for (int nj = 0; nj < 2; ++nj)
        dst[(nj << 4) + l15] = f2b(oacc[mi][nj][r] * inv);
    }
  }
}

// Out-projection GEMM (round-8-verified): C[m][n] = sum_k A[m][k]*B[n][k] + bias[n].
// BK=32, double-buffered, STAGE(next) -> compute -> full barrier. f32 out.
template<int NBN>
__global__ __launch_bounds__(256)
void mfma_gemm(const bfu* __restrict__ A, const bfu* __restrict__ B,
               const float* __restrict__ bias, float* __restrict__ out)
{
  __shared__ __align__(16) char lds[32768];
  const int t = threadIdx.x;
  const int lane = t & 63;
  const int l15 = lane & 15, l4 = lane >> 4;
  const int wid = t >> 6;
  const int wr = wid >> 1, wc = wid & 1;

  const int L = blockIdx.x;
  const int chunk = (NBN * 1024) >> 3;
  const int w = (L & 7) * chunk + (L >> 3);
  const int bm = w / NBN, bn = w % NBN;

  const int goff = (lane >> 2) * 256 + (((lane & 3) ^ ((lane >> 3) & 3)) << 3);
  const bfu* Ab = A + (((size_t)(bm * 128)) << 8) + goff;
  const bfu* Bb = B + (((size_t)(bn * 128)) << 8) + goff;

  f32x4 acc[4][4] = {};

  auto STAGE = [&](int buf, int kt) {
    char* dst = lds + (buf << 14);
    const bfu* ga = Ab + (kt << 5);
    const bfu* gb = Bb + (kt << 5);
    #pragma unroll
    for (int r = 0; r < 2; ++r) {
      int rowg = (wid << 5) + (r << 4);
      gload_lds16(ga + (size_t)rowg * 256, dst + (rowg << 6));
      gload_lds16(gb + (size_t)rowg * 256, dst + 8192 + (rowg << 6));
    }
  };

  STAGE(0, 0);
  __syncthreads();

  for (int kt = 0; kt < 8; ++kt) {
    if (kt < 7) STAGE((kt + 1) & 1, kt + 1);
    const char* bufp = lds + ((kt & 1) << 14);

    bf16x8 af[4], bfr[4];
    #pragma unroll
    for (int ms = 0; ms < 4; ++ms) {
      int row = (wr << 6) + (ms << 4) + l15;
      int u = (l4 ^ ((row >> 1) & 3)) << 4;
      af[ms] = *(const bf16x8*)(bufp + (row << 6) + u);
    }
    #pragma unroll
    for (int ns = 0; ns < 4; ++ns) {
      int row = (wc << 6) + (ns << 4) + l15;
      int u = (l4 ^ ((row >> 1) & 3)) << 4;
      bfr[ns] = *(const bf16x8*)(bufp + 8192 + (row << 6) + u);
    }
    #pragma unroll
    for (int ms = 0; ms < 4; ++ms)
      #pragma unroll
      for (int ns = 0; ns < 4; ++ns)
        acc[ms][ns] = __builtin_amdgcn_mfma_f32_16x16x32_bf16(af[ms], bfr[ns], acc[ms][ns], 0, 0, 0);
    if (kt < 7) __syncthreads();
  }

  #pragma unroll
  for (int ns = 0; ns < 4; ++ns) {
    int n = bn * 128 + (wc << 6) + (ns << 4) + l15;
    float bb = bias[n];
    #pragma unroll
    for (int ms = 0; ms < 4; ++ms) {
      int m = bm * 128 + (wr << 6) + (ms << 4) + (l4 << 2);
      #pragma unroll
      for (int r = 0; r < 4; ++r)
        out[((size_t)(m + r) << 8) + n] = acc[ms][ns][r] + bb;
    }
  }
}

extern "C" void kernel_launch(void* const* d_in, const int* in_sizes, int n_in,
                              void* d_out, int out_size, void* d_ws, size_t ws_size,
                              hipStream_t stream)
{
  const float* x     = (const float*)d_in[0];
  const float* w_qkv = (const float*)d_in[1];
  const float* b_qkv = (const float*)d_in[2];
  const float* w_out = (const float*)d_in[3];
  const float* b_out = (const float*)d_in[4];
  const float* pe    = (const float*)d_in[5];
  const int*   rel   = (const int*)d_in[6];
  float* out = (float*)d_out;

  char* ws = (char*)d_ws;
  bfu*   attn_ws = (bfu*)(ws);                 // [131072][256] bf16 = 64 MiB
  float* bias_ws = (float*)(ws + 67108864);    // 4096 f32
  bfu*   wqB     = (bfu*)(ws + 67125248);      // 196608 bf16 [768][256]
  bfu*   woB     = (bfu*)(ws + 67518464);      // 65536 bf16 [256][256]

  prep_kernel<<<768, 256, 0, stream>>>(w_qkv, w_out, pe, rel, wqB, woB, bias_ws);
  qkv_attn<<<2048, 512, 0, stream>>>(x, wqB, b_qkv, bias_ws, attn_ws);
  mfma_gemm<2><<<2048, 256, 0, stream>>>(attn_ws, woB, b_out, out);
}